// Round 13
// baseline (364.343 us; speedup 1.0000x reference)
//
#include <hip/hip_runtime.h>

#define N_SERVICES 50000
#define N_PAD      50048   // 782*64
#define N_EDGES    1600000
#define N_CTX      6144    // BATCH*CONTEXT
#define EMB        32
#define BATCH      2048
#define FIN        128     // (CONTEXT+1)*EMB
#define N_TILES    782
#define BM         128
#define M_CHUNKS   16      // 2048 / BM
#define N_CHAINS   64
#define GEMM_BLKS  (M_CHUNKS * N_CHAINS)   // 1024
#define RUN_BASE   12      // 782 = 64*12 + 14 -> first 14 chains take 13 tiles
#define RUN_EXTRA  14
#define CE_BLKS    ((N_EDGES / 4 + 255) / 256)

typedef __attribute__((ext_vector_type(4))) float f32x4;
typedef __attribute__((ext_vector_type(2))) float f32x2;
typedef __attribute__((ext_vector_type(8))) short short8;

__device__ inline unsigned short f2bf(float f) {
    unsigned u = __float_as_uint(f);
    unsigned r = (u + 0x7FFFu + ((u >> 16) & 1u)) >> 16;
    return (unsigned short)r;
}
__device__ inline float bf2f(unsigned short b) {
    return __uint_as_float(((unsigned)b) << 16);
}

// ---------------- degree count (int4: 4 edges/thread) ----------------

__global__ void k_count_degi(const int* __restrict__ dst, int* __restrict__ degi) {
    int e4 = (blockIdx.x * 256 + threadIdx.x) * 4;
    if (e4 < N_EDGES) {            // N_EDGES%4==0: all-or-nothing
        int4 d = *(const int4*)(dst + e4);
        atomicAdd(&degi[d.x], 1);
        atomicAdd(&degi[d.y], 1);
        atomicAdd(&degi[d.z], 1);
        atomicAdd(&degi[d.w], 1);
    }
}

// ---------------- scan pass 1; dis folded in ----------------

__global__ void k_scan_block(const int* __restrict__ degi, float* __restrict__ dis,
                             int* __restrict__ tmp, int* __restrict__ blocksum) {
    __shared__ int s[256];
    int t = threadIdx.x, i = blockIdx.x * 256 + t;
    int v = (i < N_SERVICES) ? degi[i] : 0;
    if (i < N_SERVICES) dis[i] = rsqrtf((float)(v + 1));  // +1 self-loop
    s[t] = v;
    __syncthreads();
#pragma unroll
    for (int o = 1; o < 256; o <<= 1) {
        int x = 0;
        if (t >= o) x = s[t - o];
        __syncthreads();
        if (t >= o) s[t] += x;
        __syncthreads();
    }
    if (i < N_SERVICES) tmp[i] = s[t] - v;       // exclusive within block
    if (t == 255) blocksum[blockIdx.x] = s[255];
}

// ---------------- fused: scan finish (+ctx list build)  ∥  layer-1 transform ----

__global__ __launch_bounds__(256) void k_scanfin_tf(
    const int* __restrict__ tmp, const int* __restrict__ blocksum,
    int* __restrict__ row_start, int* __restrict__ cursor,
    const int* __restrict__ ctx_idx, int* __restrict__ mask,
    int* __restrict__ ctx_list, int* __restrict__ ctx_count,
    const float* __restrict__ in, const float* __restrict__ W1,
    const float* __restrict__ dis, unsigned short* __restrict__ h) {
    __shared__ int s[256];
    __shared__ float Ws[EMB][EMB + 1];
    __shared__ float rows[8][EMB];
    int t = threadIdx.x;

    if (blockIdx.x < 196) {
        int v = (t < 196) ? blocksum[t] : 0;
        s[t] = v;
        __syncthreads();
#pragma unroll
        for (int o = 1; o < 256; o <<= 1) {
            int x = 0;
            if (t >= o) x = s[t - o];
            __syncthreads();
            if (t >= o) s[t] += x;
            __syncthreads();
        }
        int prefix = (blockIdx.x == 0) ? 0 : s[blockIdx.x - 1];
        int i = blockIdx.x * 256 + t;
        if (i < N_SERVICES) {
            int r = tmp[i] + prefix;
            row_start[i] = r;
            cursor[i] = r;
        }
        if (i < N_CTX) {
            int n = ctx_idx[i];
            if (atomicExch(&mask[n], 1) == 0)
                ctx_list[atomicAdd(ctx_count, 1)] = n;
        }
        if (i == 0) row_start[N_SERVICES] = N_EDGES;
    } else {
        int j = t & 31, li = t >> 5;
        for (int i = t; i < EMB * EMB; i += 256) Ws[i >> 5][i & 31] = W1[i];
        int node = (blockIdx.x - 196) * 8 + li;
        if (node < N_SERVICES) rows[li][j] = in[node * EMB + j];
        __syncthreads();
        if (node < N_SERVICES) {
            float acc = 0.f;
#pragma unroll
            for (int k = 0; k < EMB; ++k) acc = fmaf(rows[li][k], Ws[k][j], acc);
            h[node * EMB + j] = f2bf(acc * dis[node]);
        }
    }
}

// ---------------- CSR fill (int4: 4 edges/thread) ----------------

__global__ void k_fill(const int* __restrict__ src, const int* __restrict__ dst,
                       int* __restrict__ cursor, int* __restrict__ csr_src) {
    int e4 = (blockIdx.x * 256 + threadIdx.x) * 4;
    if (e4 < N_EDGES) {
        int4 s = *(const int4*)(src + e4);
        int4 d = *(const int4*)(dst + e4);
        csr_src[atomicAdd(&cursor[d.x], 1)] = s.x;
        csr_src[atomicAdd(&cursor[d.y], 1)] = s.y;
        csr_src[atomicAdd(&cursor[d.z], 1)] = s.z;
        csr_src[atomicAdd(&cursor[d.w], 1)] = s.w;
    }
}

// ---------------- fused layer-1 agg + ReLU + layer-2 transform ----------------

__global__ __launch_bounds__(256) void k_agg_tf(
    const int* __restrict__ row_start, const int* __restrict__ csr_src,
    const float* __restrict__ dis, const unsigned int* __restrict__ h2,
    const float* __restrict__ b, const float* __restrict__ W2,
    unsigned short* __restrict__ hout) {
    __shared__ float gr[16][33];
    __shared__ float Ws[32][33];
    int t = threadIdx.x;
    for (int i = t; i < EMB * EMB; i += 256) Ws[i >> 5][i & 31] = W2[i];

    int j2 = t & 15;                       // dim pair
    int local = t >> 4;
    int node = blockIdx.x * 16 + local;
    int e = row_start[node], e1 = row_start[node + 1];
    float al0 = 0.f, ah0 = 0.f, al1 = 0.f, ah1 = 0.f;
    float al2 = 0.f, ah2 = 0.f, al3 = 0.f, ah3 = 0.f;
    for (; e + 4 <= e1; e += 4) {
        int s0 = csr_src[e], s1 = csr_src[e + 1], s2 = csr_src[e + 2], s3 = csr_src[e + 3];
        unsigned v0 = h2[s0 * 16 + j2], v1 = h2[s1 * 16 + j2];
        unsigned v2 = h2[s2 * 16 + j2], v3 = h2[s3 * 16 + j2];
        al0 += bf2f((unsigned short)(v0 & 0xffff)); ah0 += bf2f((unsigned short)(v0 >> 16));
        al1 += bf2f((unsigned short)(v1 & 0xffff)); ah1 += bf2f((unsigned short)(v1 >> 16));
        al2 += bf2f((unsigned short)(v2 & 0xffff)); ah2 += bf2f((unsigned short)(v2 >> 16));
        al3 += bf2f((unsigned short)(v3 & 0xffff)); ah3 += bf2f((unsigned short)(v3 >> 16));
    }
    for (; e < e1; ++e) {
        unsigned v0 = h2[csr_src[e] * 16 + j2];
        al0 += bf2f((unsigned short)(v0 & 0xffff)); ah0 += bf2f((unsigned short)(v0 >> 16));
    }
    float dn = dis[node];
    unsigned vn = h2[node * 16 + j2];
    float lo = dn * ((al0 + al1) + (al2 + al3) + bf2f((unsigned short)(vn & 0xffff))) + b[j2 * 2];
    float hi = dn * ((ah0 + ah1) + (ah2 + ah3) + bf2f((unsigned short)(vn >> 16))) + b[j2 * 2 + 1];
    gr[local][j2 * 2]     = fmaxf(lo, 0.f);
    gr[local][j2 * 2 + 1] = fmaxf(hi, 0.f);
    __syncthreads();

    // phase 2: transform the block's 16 g1 rows by W2; 2 nodes per thread
    int d = t & 31;
    int l0 = t >> 5;                       // 0..7
    float s0 = 0.f, s1 = 0.f;
#pragma unroll
    for (int k = 0; k < EMB; ++k) {
        float w = Ws[k][d];
        s0 = fmaf(gr[l0][k], w, s0);
        s1 = fmaf(gr[l0 + 8][k], w, s1);
    }
    int n0 = blockIdx.x * 16 + l0;
    hout[(size_t)n0 * EMB + d]       = f2bf(s0 * dis[n0]);
    hout[(size_t)(n0 + 8) * EMB + d] = f2bf(s1 * dis[n0 + 8]);
}

// ---------------- layer-2 agg over the compact ctx list ----------------

__global__ void k_agg_ctx(const int* __restrict__ row_start, const int* __restrict__ csr_src,
                          const float* __restrict__ dis, const unsigned int* __restrict__ h2,
                          const float* __restrict__ b, const int* __restrict__ ctx_list,
                          const int* __restrict__ ctx_count, float* __restrict__ out) {
    int t = threadIdx.x;
    int j2 = t & 15;
    int slot = blockIdx.x * 16 + (t >> 4);
    if (slot >= *ctx_count) return;
    int node = ctx_list[slot];
    int e = row_start[node], e1 = row_start[node + 1];
    float al0 = 0.f, ah0 = 0.f, al1 = 0.f, ah1 = 0.f;
    float al2 = 0.f, ah2 = 0.f, al3 = 0.f, ah3 = 0.f;
    for (; e + 4 <= e1; e += 4) {
        int s0 = csr_src[e], s1 = csr_src[e + 1], s2 = csr_src[e + 2], s3 = csr_src[e + 3];
        unsigned v0 = h2[s0 * 16 + j2], v1 = h2[s1 * 16 + j2];
        unsigned v2 = h2[s2 * 16 + j2], v3 = h2[s3 * 16 + j2];
        al0 += bf2f((unsigned short)(v0 & 0xffff)); ah0 += bf2f((unsigned short)(v0 >> 16));
        al1 += bf2f((unsigned short)(v1 & 0xffff)); ah1 += bf2f((unsigned short)(v1 >> 16));
        al2 += bf2f((unsigned short)(v2 & 0xffff)); ah2 += bf2f((unsigned short)(v2 >> 16));
        al3 += bf2f((unsigned short)(v3 & 0xffff)); ah3 += bf2f((unsigned short)(v3 >> 16));
    }
    for (; e < e1; ++e) {
        unsigned v0 = h2[csr_src[e] * 16 + j2];
        al0 += bf2f((unsigned short)(v0 & 0xffff)); ah0 += bf2f((unsigned short)(v0 >> 16));
    }
    float dn = dis[node];
    unsigned vn = h2[node * 16 + j2];
    float lo = dn * ((al0 + al1) + (al2 + al3) + bf2f((unsigned short)(vn & 0xffff))) + b[j2 * 2];
    float hi = dn * ((ah0 + ah1) + (ah2 + ah3) + bf2f((unsigned short)(vn >> 16))) + b[j2 * 2 + 1];
    f32x2 o; o.x = lo; o.y = hi;
    *(f32x2*)&out[node * EMB + j2 * 2] = o;
}

// ---------------- feature gather (emit bf16) ----------------

__global__ void k_gather(const int* __restrict__ user_idx, const int* __restrict__ ctx_idx,
                         const float* __restrict__ user_emb, const float* __restrict__ g2,
                         unsigned short* __restrict__ x) {
    int t = blockIdx.x * 256 + threadIdx.x;  // grid exact: BATCH*FIN
    int b = t >> 7, p = t & 127;
    float v;
    if (p < EMB) {
        v = user_emb[user_idx[b] * EMB + p];
    } else {
        int c = (p - EMB) >> 5, j = p & 31;
        v = g2[ctx_idx[b * 3 + c] * EMB + j];
    }
    x[t] = f2bf(v);
}

// ---------------- fc_W transpose+convert + zero degi/mask/ctx_count ----------------

__global__ __launch_bounds__(256) void k_cvtW(const float* __restrict__ W,
                                              short* __restrict__ Wt,
                                              int* __restrict__ degi,
                                              int* __restrict__ mask,
                                              int* __restrict__ ctx_count) {
    int gid = blockIdx.x * 256 + threadIdx.x;
    if (gid < N_SERVICES) { degi[gid] = 0; mask[gid] = 0; }
    if (gid == 0) *ctx_count = 0;

    __shared__ short lds[128][33];
    int t = threadIdx.x;
    int n0 = blockIdx.x * 32;
    int nx = t & 31;
    int n  = n0 + nx;
    int kg = t >> 5;                 // 0..7
#pragma unroll
    for (int r = 0; r < 16; ++r) {
        int k = r * 8 + kg;
        float v = (n < N_SERVICES) ? W[k * N_SERVICES + n] : 0.f;
        lds[k][nx] = (short)f2bf(v);
    }
    __syncthreads();
    int nr = t >> 3;                 // 0..31
    int kc = (t & 7) * 16;
    short tmp[16];
#pragma unroll
    for (int i = 0; i < 16; ++i) tmp[i] = lds[kc + i][nr];
    short8* dstp = (short8*)(Wt + (size_t)(n0 + nr) * FIN + kc);
    dstp[0] = *(short8*)&tmp[0];
    dstp[1] = *(short8*)&tmp[8];
}

// ---------------- final GEMM: persistent, BM=128, PAIRED tiles -> 512B row runs ----
// Tiles processed in pairs: tile nt -> LDS buf0, tile nt+1 -> LDS buf1, one
// barrier, then each row stores 2 adjacent f32x4's = 512B contiguous per row
// (vs 256B before) -> half the HBM write page-misses. Next pair's B frags are
// loaded before the barrier so they arrive under the store phase.

__global__ __launch_bounds__(256, 2) void k_gemm3(
    const short* __restrict__ A, const short* __restrict__ Bt,
    const float* __restrict__ bias, float* __restrict__ out) {
    __shared__ float tile[2][BM][68];      // 2 x 34,816 B (pair of n-tiles)
    int t = threadIdx.x;
    int w = t >> 6;
    int l = t & 63;
    int lr = l & 15;
    int lg = l >> 4;
    int mc = blockIdx.x >> 6;
    int c  = blockIdx.x & (N_CHAINS - 1);
    int nt0 = c * RUN_BASE + (c < RUN_EXTRA ? c : RUN_EXTRA);
    int cnt = RUN_BASE + (c < RUN_EXTRA ? 1 : 0);
    int m_base = mc * BM;

    short8 a[8][4];
#pragma unroll
    for (int mi = 0; mi < 8; ++mi) {
        const short* arow = A + (size_t)(m_base + mi * 16 + lr) * FIN + lg * 8;
#pragma unroll
        for (int ks = 0; ks < 4; ++ks) a[mi][ks] = *(const short8*)(arow + ks * 32);
    }

    const short* bbase = Bt + (size_t)(w * 16 + lr) * FIN + lg * 8;
    short8 b0[4], b1[4], bn0[4], bn1[4];
    {
        const short* p0 = bbase + (size_t)nt0 * 64 * FIN;
        const short* p1 = bbase + (size_t)(nt0 + 1) * 64 * FIN;
#pragma unroll
        for (int ks = 0; ks < 4; ++ks) {
            b0[ks] = *(const short8*)(p0 + ks * 32);
            b1[ks] = *(const short8*)(p1 + ks * 32);   // cnt >= 12 always
        }
    }

    int scol = lr * 4;                     // store-phase block-local col (f32x4)
    int npairs = cnt >> 1;
    int nend = nt0 + cnt;

    for (int pi = 0; pi < npairs; ++pi) {
        int nt = nt0 + pi * 2;
        // compute both tiles of the pair
#pragma unroll
        for (int mi = 0; mi < 8; ++mi) {
            f32x4 acc = {};
#pragma unroll
            for (int ks = 0; ks < 4; ++ks)
                acc = __builtin_amdgcn_mfma_f32_16x16x32_bf16(b0[ks], a[mi][ks], acc, 0, 0, 0);
            *(f32x4*)&tile[0][mi * 16 + lr][w * 16 + lg * 4] = acc;
        }
#pragma unroll
        for (int mi = 0; mi < 8; ++mi) {
            f32x4 acc = {};
#pragma unroll
            for (int ks = 0; ks < 4; ++ks)
                acc = __builtin_amdgcn_mfma_f32_16x16x32_bf16(b1[ks], a[mi][ks], acc, 0, 0, 0);
            *(f32x4*)&tile[1][mi * 16 + lr][w * 16 + lg * 4] = acc;
        }
        // prefetch next pair before the barrier (drains under store phase)
        {
            int ntn = nt + 2;
            if (ntn < nend) {
                const short* p0 = bbase + (size_t)ntn * 64 * FIN;
#pragma unroll
                for (int ks = 0; ks < 4; ++ks) bn0[ks] = *(const short8*)(p0 + ks * 32);
            }
            if (ntn + 1 < nend) {
                const short* p1 = bbase + (size_t)(ntn + 1) * 64 * FIN;
#pragma unroll
                for (int ks = 0; ks < 4; ++ks) bn1[ks] = *(const short8*)(p1 + ks * 32);
            }
        }
        __syncthreads();
        // store: per row, 2 adjacent f32x4 = 512B contiguous across the pair
        {
            int gcol = nt * 64 + scol;
            bool ok0 = gcol < N_SERVICES;        // 50000%4==0: all-in or all-out
            bool ok1 = gcol + 64 < N_SERVICES;
            f32x4 bv0 = {}, bv1 = {};
            if (ok0) bv0 = *(const f32x4*)&bias[gcol];
            if (ok1) bv1 = *(const f32x4*)&bias[gcol + 64];
            float* ob = out + (size_t)m_base * N_SERVICES + gcol;
#pragma unroll
            for (int si = 0; si < 8; ++si) {
                int row = w * 32 + si * 4 + lg;
                float* orow = ob + (size_t)row * N_SERVICES;
                if (ok0) {
                    f32x4 v0 = *(const f32x4*)&tile[0][row][scol] + bv0;
                    __builtin_nontemporal_store(v0, (f32x4*)orow);
                }
                if (ok1) {
                    f32x4 v1 = *(const f32x4*)&tile[1][row][scol] + bv1;
                    __builtin_nontemporal_store(v1, (f32x4*)(orow + 64));
                }
            }
        }
        __syncthreads();
#pragma unroll
        for (int ks = 0; ks < 4; ++ks) { b0[ks] = bn0[ks]; b1[ks] = bn1[ks]; }
    }

    if (cnt & 1) {                         // tail tile (cnt=13 chains)
        int nt = nend - 1;                 // b0 holds it via the last prefetch
#pragma unroll
        for (int mi = 0; mi < 8; ++mi) {
            f32x4 acc = {};
#pragma unroll
            for (int ks = 0; ks < 4; ++ks)
                acc = __builtin_amdgcn_mfma_f32_16x16x32_bf16(b0[ks], a[mi][ks], acc, 0, 0, 0);
            *(f32x4*)&tile[0][mi * 16 + lr][w * 16 + lg * 4] = acc;
        }
        __syncthreads();
        int gcol = nt * 64 + scol;
        bool ok = gcol < N_SERVICES;
        f32x4 bv = {};
        if (ok) bv = *(const f32x4*)&bias[gcol];
        float* ob = out + (size_t)m_base * N_SERVICES + gcol;
#pragma unroll
        for (int si = 0; si < 8; ++si) {
            int row = w * 32 + si * 4 + lg;
            if (ok) {
                f32x4 v = *(const f32x4*)&tile[0][row][scol] + bv;
                __builtin_nontemporal_store(v, (f32x4*)(ob + (size_t)row * N_SERVICES));
            }
        }
    }
}

// ---------------- launch ----------------

extern "C" void kernel_launch(void* const* d_in, const int* in_sizes, int n_in,
                              void* d_out, int out_size, void* d_ws, size_t ws_size,
                              hipStream_t stream) {
    const int*   user_idx    = (const int*)d_in[0];
    const int*   ctx_idx     = (const int*)d_in[1];
    const int*   ei          = (const int*)d_in[2];
    const float* user_emb    = (const float*)d_in[3];
    const float* service_emb = (const float*)d_in[4];
    const float* W1          = (const float*)d_in[5];
    const float* b1          = (const float*)d_in[6];
    const float* W2          = (const float*)d_in[7];
    const float* b2          = (const float*)d_in[8];
    const float* fcW         = (const float*)d_in[9];
    const float* fcb         = (const float*)d_in[10];
    float* out = (float*)d_out;

    const int* src = ei;
    const int* dst = ei + N_EDGES;

    char* ws = (char*)d_ws;
    float*          dis       = (float*)(ws);                    // 200,000
    unsigned short* h1        = (unsigned short*)(ws + 200000);  // 3,200,000 (bf16 h1')
    unsigned short* h2b       = (unsigned short*)(ws + 3400000); // 3,200,000 (bf16 h2')
    float*          g         = (float*)(ws + 6600000);          // 6,400,000 (g2, ctx rows only)
    unsigned short* xb        = (unsigned short*)(ws + 13000000);//   524,288
    int*            degi      = (int*)(ws + 13000000);           // 200,000 overlay (dead before k_gather)
    short*          Wt        = (short*)(ws + 13524288);         // 12,812,288
    int*            row_start = (int*)(ws + 26336576);           // 200,004
    int*            cursor    = (int*)(ws + 26536580);           // 200,000
    int*            csr_src   = (int*)(ws + 26736580);           // 6,400,000
    int*            tmp       = (int*)(ws + 26736580);           // 200,000 overlay (dead before k_fill)
    int*            blocksum  = (int*)(ws + 33136580);           // 1,024
    int*            mask      = (int*)(ws + 33137604);           // 200,000
    int*            ctx_list  = (int*)(ws + 33337604);           // 24,576
    int*            ctx_count = (int*)(ws + 33362180);           // 4     (total ~33.4 MB)

    // cvtW also zeroes degi + mask + ctx_count (runs first)
    k_cvtW<<<N_PAD / 32, 256, 0, stream>>>(fcW, Wt, degi, mask, ctx_count);

    // CSR build
    k_count_degi<<<CE_BLKS, 256, 0, stream>>>(dst, degi);
    k_scan_block<<<196, 256, 0, stream>>>(degi, dis, tmp, blocksum);
    // fused: scan finish + ctx-list build (blocks 0..195)  ∥  layer-1 transform
    k_scanfin_tf<<<196 + 6250, 256, 0, stream>>>(tmp, blocksum, row_start, cursor,
                                                 ctx_idx, mask, ctx_list, ctx_count,
                                                 service_emb, W1, dis, h1);
    k_fill<<<CE_BLKS, 256, 0, stream>>>(src, dst, cursor, csr_src);

    // fused layer-1 agg + ReLU + layer-2 transform (g1 never leaves LDS)
    k_agg_tf<<<3125, 256, 0, stream>>>(row_start, csr_src, dis,
                                       (const unsigned int*)h1, b1, W2, h2b);
    // layer-2 agg over compact ctx list
    k_agg_ctx<<<N_CTX / 16, 256, 0, stream>>>(row_start, csr_src, dis,
                                              (const unsigned int*)h2b, b2,
                                              ctx_list, ctx_count, g);

    k_gather<<<BATCH * FIN / 256, 256, 0, stream>>>(user_idx, ctx_idx, user_emb, g, xb);

    k_gemm3<<<GEMM_BLKS, 256, 0, stream>>>((const short*)xb, Wt, fcb, out);
}